// Round 9
// baseline (1571.784 us; speedup 1.0000x reference)
//
#include <hip/hip_runtime.h>
#include <hip/hip_bf16.h>
#include <stdint.h>

using bf16 = __hip_bfloat16;

typedef __bf16 bf16x8 __attribute__((ext_vector_type(8)));
typedef float  f32x4  __attribute__((ext_vector_type(4)));

constexpr float SCALE = 0.08838834764831845f;  // 1/sqrt(128)
constexpr size_t CTR_OFF = 93323264;           // barrier counters (64 B)

// async global->LDS, 16B per lane, wave-uniform LDS base + lane*16 scatter
#define GLDS16(gp, lp)                                               \
  __builtin_amdgcn_global_load_lds(                                  \
      (const __attribute__((address_space(1))) void*)(gp),           \
      (__attribute__((address_space(3))) void*)(lp), 16, 0, 0)

// ---------------------------------------------------------------------------
// Device-scope grid barrier (all gridDim.x blocks MUST be co-resident;
// guaranteed here by __launch_bounds__(256,2) and grid=512=2*256CU).
// Counters pre-zeroed by hipMemsetAsync before launch.
// ---------------------------------------------------------------------------
__device__ __forceinline__ void gbar(unsigned* ctr, unsigned target)
{
  __threadfence();    // flush this block's stores toward coherence point
  __syncthreads();    // all block stores complete (vmcnt drain) before arrival
  if (threadIdx.x == 0) {
    __hip_atomic_fetch_add(ctr, 1u, __ATOMIC_RELEASE, __HIP_MEMORY_SCOPE_AGENT);
    while (__hip_atomic_load(ctr, __ATOMIC_ACQUIRE, __HIP_MEMORY_SCOPE_AGENT) < target)
      __builtin_amdgcn_s_sleep(2);
  }
  __syncthreads();
  __threadfence();    // invalidate stale cache lines before consuming
}

// ---------------------------------------------------------------------------
// BT-GEMM core (m97 structure): acc[m][n] += sum_k A[m][k] * B[n][k]
// 128x128 tile, 256 threads = 4 waves (64x64 quadrant each, 4x4 MFMA tiles).
// ---------------------------------------------------------------------------
__device__ __forceinline__ void gemm_bt_core(
    const bf16* __restrict__ Abase, int lda,
    const bf16* __restrict__ Bbase, int ldb,
    int kIters, f32x4 (&acc)[4][4])
{
  alignas(16) __shared__ bf16 As[128 * 32];
  alignas(16) __shared__ bf16 Bs[128 * 32];
  const int t    = threadIdx.x;
  const int lane = t & 63;
  const int quad = lane >> 4, r16 = lane & 15;
  const int wave = t >> 6;
  const int wm = (wave & 1) * 64, wn = (wave >> 1) * 64;
  const int lrow = lane >> 2;
  const int lk   = (lane & 3) * 8;

  const long aOff0 = (long)(wave * 32 + lrow) * lda + lk;
  const long aOff1 = aOff0 + 16l * lda;
  const long bOff0 = (long)(wave * 32 + lrow) * ldb + lk;
  const long bOff1 = bOff0 + 16l * ldb;
  bf16* aL0 = &As[(wave * 32) * 32];
  bf16* aL1 = &As[(wave * 32 + 16) * 32];
  bf16* bL0 = &Bs[(wave * 32) * 32];
  bf16* bL1 = &Bs[(wave * 32 + 16) * 32];

#pragma unroll
  for (int i = 0; i < 4; i++)
#pragma unroll
    for (int j = 0; j < 4; j++) acc[i][j] = {0.f, 0.f, 0.f, 0.f};

  for (int ks = 0; ks < kIters; ++ks) {
    const int k0 = ks * 32;
    __syncthreads();
    GLDS16(Abase + k0 + aOff0, aL0);
    GLDS16(Abase + k0 + aOff1, aL1);
    GLDS16(Bbase + k0 + bOff0, bL0);
    GLDS16(Bbase + k0 + bOff1, bL1);
    __syncthreads();
    bf16x8 af[4], bfr[4];
#pragma unroll
    for (int i = 0; i < 4; i++)
      af[i] = *(const bf16x8*)&As[(wm + i * 16 + r16) * 32 + quad * 8];
#pragma unroll
    for (int j = 0; j < 4; j++)
      bfr[j] = *(const bf16x8*)&Bs[(wn + j * 16 + r16) * 32 + quad * 8];
#pragma unroll
    for (int i = 0; i < 4; i++)
#pragma unroll
      for (int j = 0; j < 4; j++)
        acc[i][j] = __builtin_amdgcn_mfma_f32_16x16x32_bf16(af[i], bfr[j], acc[i][j], 0, 0, 0);
  }
}

__device__ __forceinline__ void store_bf16_tile(
    f32x4 (&acc)[4][4], bf16* __restrict__ Cp, int ldc, float mul = 1.0f)
{
  const int t = threadIdx.x;
  const int lane = t & 63;
  const int quad = lane >> 4, r16 = lane & 15;
  const int wave = t >> 6;
  const int wm = (wave & 1) * 64, wn = (wave >> 1) * 64;
#pragma unroll
  for (int i = 0; i < 4; i++)
#pragma unroll
    for (int j = 0; j < 4; j++)
#pragma unroll
      for (int r = 0; r < 4; r++) {
        const int row = wm + i * 16 + quad * 4 + r;
        const int col = wn + j * 16 + r16;
        Cp[(long)row * ldc + col] = __float2bfloat16(acc[i][j][r] * mul);
      }
}

__device__ __forceinline__ void store_f32_tile(
    f32x4 (&acc)[4][4], float* __restrict__ Cp, int ldc)
{
  const int t = threadIdx.x;
  const int lane = t & 63;
  const int quad = lane >> 4, r16 = lane & 15;
  const int wave = t >> 6;
  const int wm = (wave & 1) * 64, wn = (wave >> 1) * 64;
#pragma unroll
  for (int i = 0; i < 4; i++)
#pragma unroll
    for (int j = 0; j < 4; j++)
#pragma unroll
      for (int r = 0; r < 4; r++) {
        const int row = wm + i * 16 + quad * 4 + r;
        const int col = wn + j * 16 + r16;
        Cp[(long)row * ldc + col] = acc[i][j][r];
      }
}

// triangular tile decode: u in [0,36) -> (ti,tj), ti<=tj, 8x8 upper triangle
__device__ __forceinline__ void tri_decode(int tt, int& ti, int& tj)
{
  ti = 0;
  while (tt >= 8 - ti) { tt -= 8 - ti; ++ti; }
  tj = ti + tt;
}

// ---------------------------------------------------------------------------
// Single persistent kernel, custom grid barriers, all stages grid-stride:
// prep -> G(splitK x3, upper-tri) -> redG -> P(splitK x2) -> redP -> mt ->
// w2 -> w3 -> out.   out = sum_h scale*Wout_h.Wv_h.G.Wk_h^T.Wq_h.x, G=x.x^T
// ---------------------------------------------------------------------------
__global__ __launch_bounds__(256, 2) void k_mega(
    const float* __restrict__ x, const float* __restrict__ Wqkv,
    const float* __restrict__ Wout, float* __restrict__ out,
    char* __restrict__ ws)
{
  float* scratchF = (float*)ws;                 // Gp 28.3MB / Pp 33.6MB
  bf16*  W2    = (bf16*)ws;                     //  8.4MB (gen 3, aliases scratch)
  bf16*  W3    = (bf16*)(ws + 8388608);         //  8.4MB (gen 3)
  bf16*  xc    = (bf16*)(ws + 33554432);        // 16.8MB  x bf16 (c,s)
  bf16*  xT    = (bf16*)(ws + 50331648);        // 16.8MB  x^T bf16 (s,c)
  bf16*  G     = (bf16*)(ws + 67108864);        //  8.4MB
  bf16*  P     = (bf16*)(ws + 75497472);        //  8.4MB
  bf16*  WkvB  = (bf16*)(ws + 83886080);        //  4.2MB
  bf16*  WoutB = (bf16*)(ws + 88080384);        //  2.1MB
  bf16*  WqT   = (bf16*)(ws + 90177536);        //  2.1MB
  bf16*  MbT   = (bf16*)(ws + 92274688);        //  1.0MB (end 93,323,264)
  unsigned* ctr = (unsigned*)(ws + CTR_OFF);    // 16 barrier counters

  const int bid = blockIdx.x, tid = threadIdx.x;
  const int NB = gridDim.x;
  const unsigned TGT = (unsigned)gridDim.x;

  // ---- stage 1: prep (xc + xT, WqT transposes; WkvB/WoutB converts) ----
  {
    __shared__ bf16 tile[32][33];
    const int tx = tid & 31, ty = tid >> 5;
    for (int u = bid; u < 12288; u += NB) {
      if (u < 8192) {
        const int b = u >> 11, rem = u & 2047;
        const int c0 = (rem & 63) * 32, r0 = (rem >> 6) * 32;  // c0 over s, r0 over c
        const float* ip = x + (long)b * 2097152;
        bf16* oc = xc + (long)b * 2097152;
        bf16* ot = xT + (long)b * 2097152;
#pragma unroll
        for (int i = 0; i < 32; i += 8) {
          bf16 vb = __float2bfloat16(ip[(long)(r0 + ty + i) * 2048 + c0 + tx]);
          oc[(long)(r0 + ty + i) * 2048 + c0 + tx] = vb;
          tile[ty + i][tx] = vb;
        }
        __syncthreads();
#pragma unroll
        for (int i = 0; i < 32; i += 8)
          ot[(long)(c0 + ty + i) * 1024 + r0 + tx] = tile[tx][ty + i];
        __syncthreads();
      } else if (u < 9216) {
        const int v = u - 8192;
        const int c0 = (v & 31) * 32, r0 = (v >> 5) * 32;
#pragma unroll
        for (int i = 0; i < 32; i += 8)
          tile[ty + i][tx] = __float2bfloat16(Wqkv[(long)(r0 + ty + i) * 1024 + c0 + tx]);
        __syncthreads();
#pragma unroll
        for (int i = 0; i < 32; i += 8)
          WqT[(long)(c0 + ty + i) * 1024 + r0 + tx] = tile[tx][ty + i];
        __syncthreads();
      } else {
        const long lin = (long)(u - 9216) * 256 + tid;  // < 786432
        const bool isKV = lin < 524288;
        const float4 f = isKV ? ((const float4*)(Wqkv + 1048576))[lin]
                              : ((const float4*)Wout)[lin - 524288];
        bf16 tmp[4] = {__float2bfloat16(f.x), __float2bfloat16(f.y),
                       __float2bfloat16(f.z), __float2bfloat16(f.w)};
        if (isKV) ((ushort4*)WkvB)[lin] = *(ushort4*)tmp;
        else      ((ushort4*)WoutB)[lin - 524288] = *(ushort4*)tmp;
      }
    }
  }
  gbar(&ctr[0], TGT);

  // ---- stage 2: Gp = x.x^T, upper-tri tiles, split-K x3 (432 units) ----
  {
    const int kEdge[4] = {0, 22, 43, 64};  // 64 kIters split 22/21/21
    for (int u = bid; u < 432; u += NB) {
      const int chunk = u / 144, idx = u % 144, b = idx / 36;
      int ti, tj;
      tri_decode(idx % 36, ti, tj);
      const bf16* xb = xc + (long)b * 2097152;
      const int kOff = kEdge[chunk] * 32;
      f32x4 acc[4][4];
      gemm_bt_core(xb + (long)(ti * 128) * 2048 + kOff, 2048,
                   xb + (long)(tj * 128) * 2048 + kOff, 2048,
                   kEdge[chunk + 1] - kEdge[chunk], acc);
      store_f32_tile(acc, scratchF + (long)u * 16384, 128);
    }
  }
  gbar(&ctr[1], TGT);

  // ---- stage 3: G = bf16(sum 3 chunks), mirrored to both triangles ----
  for (long lin = (long)bid * 256 + tid; lin < 2359296; lin += (long)NB * 256) {
    const int u = (int)(lin >> 14), off = (int)(lin & 16383);
    const int b = u / 36;
    int ti, tj;
    tri_decode(u % 36, ti, tj);
    float v = 0.f;
#pragma unroll
    for (int ch = 0; ch < 3; ++ch)
      v += scratchF[(long)(ch * 144 + u) * 16384 + off];
    const int r = off >> 7, c = off & 127;
    const int gr = ti * 128 + r, gc = tj * 128 + c;
    const bf16 vb = __float2bfloat16(v);
    G[(long)b * 1048576 + (long)gr * 1024 + gc] = vb;
    G[(long)b * 1048576 + (long)gc * 1024 + gr] = vb;
  }
  gbar(&ctr[2], TGT);

  // ---- stage 4: Pp = Wk_h . G[b], split-K x2 (512 units) ----
  for (int u = bid; u < 512; u += NB) {
    const int chunk = u >> 8, r = u & 255, z = r >> 3, ct = r & 7;
    const int b = z >> 3, h = z & 7;
    f32x4 acc[4][4];
    gemm_bt_core(WkvB + (long)(h * 128) * 1024 + chunk * 512, 1024,
                 G + (long)b * 1048576 + (long)(ct * 128) * 1024 + chunk * 512, 1024,
                 16, acc);
    store_f32_tile(acc, scratchF + (long)(chunk * 256 + r) * 16384, 128);
  }
  gbar(&ctr[3], TGT);

  // ---- stage 5: P[z][e][c] = bf16(sum of 2 chunks) ----
  for (long lin = (long)bid * 256 + tid; lin < 4194304; lin += (long)NB * 256) {
    const int z = (int)(lin >> 17), off = (int)(lin & 131071);
    const int r = off >> 10, c = off & 1023, ct = c >> 7, cc = c & 127;
    const float v = scratchF[(long)(z * 8 + ct) * 16384 + r * 128 + cc]
                  + scratchF[(long)(256 + z * 8 + ct) * 16384 + r * 128 + cc];
    P[(long)z * 131072 + off] = __float2bfloat16(v);
  }
  gbar(&ctr[4], TGT);

  // ---- stage 6: MbT[z] = SCALE * P[z] . Wv_h^T (32 units) ----
  for (int u = bid; u < 32; u += NB) {
    const int z = u, h = z & 7;
    f32x4 acc[4][4];
    gemm_bt_core(P + (long)z * 131072, 1024,
                 WkvB + (long)(1024 + h * 128) * 1024, 1024, 32, acc);
    store_bf16_tile(acc, MbT + (long)z * 16384, 128, SCALE);
  }
  gbar(&ctr[5], TGT);

  // ---- stage 7: W2[b] = Wout . MbT (256 units, K=128) ----
  for (int u = bid; u < 256; u += NB) {
    const int ot = u & 7, h = (u >> 3) & 7, b = u >> 6, z = b * 8 + h;
    f32x4 acc[4][4];
    gemm_bt_core(WoutB + (long)(ot * 128) * 1024 + h * 128, 1024,
                 MbT + (long)z * 16384, 128, 4, acc);
    store_bf16_tile(acc, W2 + (long)b * 1048576 + (long)(ot * 128) * 1024 + h * 128, 1024);
  }
  gbar(&ctr[6], TGT);

  // ---- stage 8: W3[b] = W2[b] . Wq (256 units) ----
  for (int u = bid; u < 256; u += NB) {
    const int ct = u & 7, ot = (u >> 3) & 7, b = u >> 6;
    f32x4 acc[4][4];
    gemm_bt_core(W2 + (long)b * 1048576 + (long)(ot * 128) * 1024, 1024,
                 WqT + (long)(ct * 128) * 1024, 1024, 32, acc);
    store_bf16_tile(acc, W3 + (long)b * 1048576 + (long)(ot * 128) * 1024 + ct * 128, 1024);
  }
  gbar(&ctr[7], TGT);

  // ---- stage 9: out[b] = W3[b] . x[b] -> f32 (512 units) ----
  for (int u = bid; u < 512; u += NB) {
    const int st = u & 15, ot = (u >> 4) & 7, b = u >> 7;
    f32x4 acc[4][4];
    gemm_bt_core(W3 + (long)b * 1048576 + (long)(ot * 128) * 1024, 1024,
                 xT + (long)b * 2097152 + (long)(st * 128) * 1024, 1024, 32, acc);
    store_f32_tile(acc, out + (long)b * 2097152 + (long)(ot * 128) * 2048 + st * 128, 2048);
  }
}

extern "C" void kernel_launch(void* const* d_in, const int* in_sizes, int n_in,
                              void* d_out, int out_size, void* d_ws, size_t ws_size,
                              hipStream_t stream)
{
  const float* x    = (const float*)d_in[0];  // (4,1024,2048) f32
  const float* Wqkv = (const float*)d_in[1];  // (3072,1024)   f32
  const float* Wout = (const float*)d_in[2];  // (1024,1024)   f32
  float* outp = (float*)d_out;                // (4,1024,2048) f32
  char* ws = (char*)d_ws;

  // zero the barrier counters (ws is poisoned 0xAA before every launch)
  hipMemsetAsync(ws + CTR_OFF, 0, 64, stream);
  // 512 blocks = 2 blocks/CU co-resident (launch_bounds(256,2): <=256 regs,
  // 16.4KB LDS/block) -> custom device-scope grid barrier is safe.
  k_mega<<<dim3(512), dim3(256), 0, stream>>>(x, Wqkv, Wout, outp, ws);
}